// Round 6
// baseline (2881.510 us; speedup 1.0000x reference)
//
#include <hip/hip_runtime.h>
#include <math.h>

#define CH    512
#define FMPX  40
#define PW    42            // padded row width
#define PADN  1764          // 42*42
#define NP    1600          // 40*40
#define BATCH 8
#define NCLS  20
#define CONF_THR 0.001f
#define NMS_THR  0.6f

typedef _Float16 v8h __attribute__((ext_vector_type(8)));
typedef float    v4f __attribute__((ext_vector_type(4)));

// ws layout (in _Float16 units): 8 feature planes (4 hi/lo pairs: X,A,B,C),
// then 2 transposed-weight sets (hi/lo each).  Total 134.5 MB.
// INVARIANT used by conv_dual: lo plane = hi plane + FPLANE (pairs adjacent).
#define FPLANE  ((size_t)BATCH * PADN * CH)          // 7,225,344 halves
#define WSZ     ((size_t)9 * CH * CH)                // 2,359,296 halves

__device__ __forceinline__ int padidx(int p) { return p + 2 * (p / FMPX) + PW + 1; }

// async global->LDS, 16 B per lane
typedef __attribute__((address_space(1))) const void* gas_t;
typedef __attribute__((address_space(3))) void*       las_t;
__device__ __forceinline__ void gl2lds16(const void* g, void* l) {
    __builtin_amdgcn_global_load_lds((gas_t)g, (las_t)l, 16, 0, 0);
}
// raw LDS byte address of a generic pointer into __shared__
__device__ __forceinline__ unsigned lds_addr(void* p) {
    return (unsigned)(uintptr_t)(las_t)p;
}
// inline-asm ds_read_b128: invisible to SIInsertWaitcnts' LDS-DMA alias
// tracking, so no spurious vmcnt drains between in-flight global_load_lds
// (future buffers) and reads of the current buffer.
__device__ __forceinline__ v8h lds_b128(unsigned a) {
    v8h r;
    asm volatile("ds_read_b128 %0, %1" : "=v"(r) : "v"(a));
    return r;
}

// ---------------------------------------------------------------------------
// Zero the padded borders of all 8 feature planes (ws re-poisoned each call).
// ---------------------------------------------------------------------------
__global__ __launch_bounds__(256)
void border_zero(uint4* __restrict__ ws) {
    int idx = blockIdx.x * 256 + threadIdx.x;
    int u    = idx & 63;
    int cell = (idx >> 6) % 164;
    int b    = (idx / (64 * 164)) & 7;
    int pl   = idx / (64 * 164 * 8);          // 0..7
    int pi;
    if (cell < 42)      pi = cell;
    else if (cell < 84) pi = 41 * PW + (cell - 42);
    else { int r = cell - 84; pi = (1 + (r >> 1)) * PW + ((r & 1) ? 41 : 0); }
    size_t hoff = (size_t)pl * FPLANE + (size_t)b * (PADN * CH) + (size_t)pi * CH;
    ws[(hoff >> 3) + u] = make_uint4(0u, 0u, 0u, 0u);
}

// ---------------------------------------------------------------------------
// x [b][512][1600] fp32 -> padded pos-major fp16 hi/lo planes [b][1764][512].
// ---------------------------------------------------------------------------
__global__ __launch_bounds__(256)
void xprep_kernel(const float* __restrict__ x, _Float16* __restrict__ Xh,
                  _Float16* __restrict__ Xl) {
    __shared__ float T[64][65];
    const int t = threadIdx.x;
    const int p0  = blockIdx.x * 64;   // 25
    const int ci0 = blockIdx.y * 64;   // 8
    const int b   = blockIdx.z;        // 8
#pragma unroll
    for (int it = 0; it < 16; ++it) {
        int row = (t >> 6) + 4 * it;
        int col = t & 63;
        T[col][row] = x[((size_t)b * CH + ci0 + row) * NP + p0 + col];
    }
    __syncthreads();
#pragma unroll
    for (int it = 0; it < 16; ++it) {
        int posl = (t >> 6) + 4 * it;
        int ci   = t & 63;
        float v = T[posl][ci];
        _Float16 h = (_Float16)v;
        _Float16 l = (_Float16)((v - (float)h) * 2048.0f);
        size_t o = (size_t)b * (PADN * CH) + (size_t)padidx(p0 + posl) * CH + ci0 + ci;
        Xh[o] = h; Xl[o] = l;
    }
}

// ---------------------------------------------------------------------------
// w [co][ci][3][3] fp32 -> Wh/Wl [tap][co][ci] fp16.
// ---------------------------------------------------------------------------
__global__ __launch_bounds__(256)
void wtrans_kernel(const float* __restrict__ w, _Float16* __restrict__ Wh,
                   _Float16* __restrict__ Wl) {
    __shared__ float tile[32][289];
    const int t = threadIdx.x;
    const int co0 = blockIdx.x * 32;   // 16
    const int ci0 = blockIdx.y * 32;   // 16
#pragma unroll
    for (int g = 0; g < 36; ++g) {     // 32*288 = 9216
        int l = t + 256 * g;
        int co = l / 288, j = l - co * 288;
        tile[co][j] = w[(size_t)(co0 + co) * 4608 + ci0 * 9 + j];
    }
    __syncthreads();
#pragma unroll
    for (int tap = 0; tap < 9; ++tap) {
#pragma unroll
        for (int cg = 0; cg < 4; ++cg) {
            int co = cg * 8 + (t >> 5);
            int ci = t & 31;
            float v = tile[co][ci * 9 + tap];
            _Float16 h = (_Float16)(16.0f * v);
            _Float16 l = (_Float16)((v - (float)h * 0.0625f) * 32768.0f);
            size_t o = ((size_t)tap * CH + co0 + co) * CH + ci0 + ci;
            Wh[o] = h; Wl[o] = l;
        }
    }
}

// ---------------------------------------------------------------------------
// Dual 3x3 conv via MFMA, split-fp16.  r2 geometry (proven):
//   block = 512 thr / 8 waves, tile 128pos x 256co, wave tile 64pos x 64co.
// ROUND-6: A-DIRECT.  The MFMA A-fragment (lane=pos, quad*8=k) is exactly
// the global layout, so A skips LDS: loaded global->regs, pipelined one
// chunk ahead (ping-pong ah; al loaded same-chunk under cluster-A's shadow).
// LDS stages B only: chunk = 32 KB, 3 buffers = 96 KB.  LDS port per chunk
// drops 176KB -> 96KB ( < MFMA 1862 cyc floor).  Counted vmcnt everywhere;
// lgkm outstanding <= 4; regs ~246 (fits 256 cap, no Fa/Fb blowup).
// Clusters: A = acc1 += ah*bh (16 MFMA); B = acc2 += ah*bl then al*bh (32).
// Per-accumulator MFMA order identical to r2 -> bit-identical output.
// vm FIFO (steady): top-of-chunk outstanding [ah(m)4, Bst(m+1)4];
//   step4 wait vmcnt(8) forces ah(m);  step9 wait vmcnt(8) forces
//   Bst(m+1)+al(m); barrier. Edges m=142/143 use vmcnt(4)/(0).
// Block decode (1D grid, nconv*208 blocks):
//   b = bid & 7 (XCD swizzle); q = bid >> 3; cid = q/26; r = q%26;
//   cos = r & 1; pt = r >> 1 (0..12); 13th pos tile ragged (guarded store)
// Per-buffer: Bh bytes [0,16384), Bl [16384,32768).
// ---------------------------------------------------------------------------
__global__ __launch_bounds__(512, 2)
void conv_dual(const _Float16* __restrict__ I0h, const _Float16* __restrict__ I0l,
               const _Float16* __restrict__ W0h, const _Float16* __restrict__ W0l,
               const float* __restrict__ bias0,
               _Float16* __restrict__ O0h, _Float16* __restrict__ O0l,
               const _Float16* __restrict__ I1h, const _Float16* __restrict__ I1l,
               const _Float16* __restrict__ W1h, const _Float16* __restrict__ W1l,
               const float* __restrict__ bias1,
               _Float16* __restrict__ O1h, _Float16* __restrict__ O1l) {
    __shared__ _Float16 sm[49152];   // 3 x 16384 halves = 96 KB
    const int t = threadIdx.x;
    const int w = t >> 6, l = t & 63;
    const int quad = l >> 4, col = l & 15;
    const int ph = w >> 2, cq = w & 3;          // wave's pos-half / co-quad

    const int bid = blockIdx.x;
    const int b   = bid & 7;
    const int q   = bid >> 3;
    const int cid = q / 26;
    const int r   = q - 26 * cid;
    const int co0 = (r & 1) * 256;
    const int p0  = (r >> 1) * 128;

    const _Float16* Ih = cid ? I1h : I0h;
    const _Float16* Wh = cid ? W1h : W0h;
    const _Float16* Wl = cid ? W1l : W0l;
    const float*  bias = cid ? bias1 : bias0;
    _Float16* Oh = cid ? O1h : O0h;
    _Float16* Ol = cid ? O1l : O0l;
    // lo input plane is hi + FPLANE (ws layout invariant, all call sites)

    const size_t boff = (size_t)b * (PADN * CH);

    // B staging source base (halves) + dest offset within buffer (halves)
    const size_t sB0 = (size_t)(co0 + 32 * w + col) * CH + quad * 8;
    const int dB = (2 * w) * 512 + l * 8;

    // B fragment read byte-addresses (buffer 0); + rotating byte offset
    const unsigned smB = lds_addr(sm);
    unsigned bRh[4], bRl[4];
#pragma unroll
    for (int j = 0; j < 4; ++j) {
        bRh[j] = smB + (cq * 4 + j) * 1024 + l * 16;
        bRl[j] = bRh[j] + 16384;
    }

    // A lane offsets (halves, fit u32)
    unsigned sAw[4];
#pragma unroll
    for (int i = 0; i < 4; ++i)
        sAw[i] = (unsigned)(boff + (size_t)padidx(p0 + (ph * 4 + i) * 16 + col) * CH + quad * 8);

    const _Float16 *pA0, *pA1, *pA2, *pA3, *pWh, *pWl;
    auto setA = [&](int ms) {
        const int tap = ms >> 4, cc = (ms & 15) << 5;
        const int ty  = tap / 3;
        const int tsh = ((ty - 1) * PW + (tap - ty * 3 - 1)) * CH + cc;
        pA0 = Ih + sAw[0] + tsh;  pA1 = Ih + sAw[1] + tsh;
        pA2 = Ih + sAw[2] + tsh;  pA3 = Ih + sAw[3] + tsh;
    };
    auto setW = [&](int ms) {
        const int tap = ms >> 4, cc = (ms & 15) << 5;
        const size_t wo = (size_t)tap * (CH * CH) + cc;
        pWh = Wh + wo + sB0;  pWl = Wl + wo + sB0;
    };
    auto stageB = [&](unsigned byteOff) {           // 4 vm ops
        _Float16* dst = (_Float16*)((char*)sm + byteOff) + dB;
        gl2lds16(pWh,           dst);
        gl2lds16(pWh + 16 * CH, dst + 512);
        gl2lds16(pWl,           dst + 8192);
        gl2lds16(pWl + 16 * CH, dst + 8192 + 512);
    };

    v4f acc1[4][4], acc2[4][4];
#pragma unroll
    for (int i = 0; i < 4; ++i)
#pragma unroll
        for (int j = 0; j < 4; ++j) {
            acc1[i][j] = (v4f){0.f, 0.f, 0.f, 0.f};
            acc2[i][j] = (v4f){0.f, 0.f, 0.f, 0.f};
        }

    unsigned c0B = 0, c1B = 32768, c2B = 65536;   // read / next / stage (bytes)

    // prologue: issue ah(0) [4 vm], stage B(0), B(1) [8 vm]; force ah0+Bst0
    v8h ahP[4], ahQ[4];
    setA(0);
    ahP[0] = *(const v8h*)pA0;  ahP[1] = *(const v8h*)pA1;
    ahP[2] = *(const v8h*)pA2;  ahP[3] = *(const v8h*)pA3;
    setW(0); stageB(0);
    setW(1); stageB(32768);
    setW(2);
    asm volatile("s_waitcnt vmcnt(4)" ::: "memory");   // ah0 + Bst0 done
    __builtin_amdgcn_s_barrier();

    auto chunk_body = [&](int m, v8h (&ah)[4], v8h (&ahN)[4]) {
        const unsigned rb = c0B;

        // bh reads (4 lgkm) from current buffer
        v8h bh[4];
        bh[0] = lds_b128(bRh[0] + rb);
        bh[1] = lds_b128(bRh[1] + rb);
        bh[2] = lds_b128(bRh[2] + rb);
        bh[3] = lds_b128(bRh[3] + rb);

        // al(m) issue (4 vm) -- lo plane = hi + FPLANE
        v8h al[4];
        al[0] = *(const v8h*)(pA0 + FPLANE);
        al[1] = *(const v8h*)(pA1 + FPLANE);
        al[2] = *(const v8h*)(pA2 + FPLANE);
        al[3] = *(const v8h*)(pA3 + FPLANE);

        // force ah(m) [oldest 4 vm] + bh reads
        if (m < 143) { asm volatile("s_waitcnt vmcnt(8) lgkmcnt(0)" ::: "memory"); }
        else         { asm volatile("s_waitcnt vmcnt(4) lgkmcnt(0)" ::: "memory"); }
        __builtin_amdgcn_sched_barrier(0);

        __builtin_amdgcn_s_setprio(1);
        // cluster A: acc1 += ah*bh (16 MFMA)
#pragma unroll
        for (int i = 0; i < 4; ++i)
            acc1[i][0] = __builtin_amdgcn_mfma_f32_16x16x32_f16(ah[i], bh[0], acc1[i][0], 0, 0, 0);
#pragma unroll
        for (int i = 0; i < 4; ++i)
            acc1[i][1] = __builtin_amdgcn_mfma_f32_16x16x32_f16(ah[i], bh[1], acc1[i][1], 0, 0, 0);
#pragma unroll
        for (int i = 0; i < 4; ++i)
            acc1[i][2] = __builtin_amdgcn_mfma_f32_16x16x32_f16(ah[i], bh[2], acc1[i][2], 0, 0, 0);
#pragma unroll
        for (int i = 0; i < 4; ++i)
            acc1[i][3] = __builtin_amdgcn_mfma_f32_16x16x32_f16(ah[i], bh[3], acc1[i][3], 0, 0, 0);
        __builtin_amdgcn_s_setprio(0);

        // bl reads (4 lgkm)
        v8h bl[4];
        bl[0] = lds_b128(bRl[0] + rb);
        bl[1] = lds_b128(bRl[1] + rb);
        bl[2] = lds_b128(bRl[2] + rb);
        bl[3] = lds_b128(bRl[3] + rb);

        // advance A ptrs to chunk m+1 and issue ah(m+1) (4 vm)
        if (m < 143) {
            if (((m + 1) & 15) == 0) setA(m + 1);
            else { pA0 += 32; pA1 += 32; pA2 += 32; pA3 += 32; }
            ahN[0] = *(const v8h*)pA0;  ahN[1] = *(const v8h*)pA1;
            ahN[2] = *(const v8h*)pA2;  ahN[3] = *(const v8h*)pA3;
        }
        // stage B(m+2) (4 vm); advance W ptrs to m+3
        if (m < 142) {
            stageB(c2B);
            const int nx = m + 3;
            if (nx < 144) {
                if ((nx & 15) == 0) setW(nx);
                else { pWh += 32; pWl += 32; }
            }
        }

        // force Bst(m+1) + al(m); leave ah(m+1), Bst(m+2) in flight
        if (m < 142)       { asm volatile("s_waitcnt vmcnt(8) lgkmcnt(0)" ::: "memory"); }
        else if (m == 142) { asm volatile("s_waitcnt vmcnt(4) lgkmcnt(0)" ::: "memory"); }
        else               { asm volatile("s_waitcnt vmcnt(0) lgkmcnt(0)" ::: "memory"); }
        __builtin_amdgcn_sched_barrier(0);

        __builtin_amdgcn_s_setprio(1);
        // cluster B: acc2 += ah*bl (16) then acc2 += al*bh (16)
#pragma unroll
        for (int j = 0; j < 4; ++j)
#pragma unroll
            for (int i = 0; i < 4; ++i)
                acc2[i][j] = __builtin_amdgcn_mfma_f32_16x16x32_f16(ah[i], bl[j], acc2[i][j], 0, 0, 0);
#pragma unroll
        for (int j = 0; j < 4; ++j)
#pragma unroll
            for (int i = 0; i < 4; ++i)
                acc2[i][j] = __builtin_amdgcn_mfma_f32_16x16x32_f16(al[i], bh[j], acc2[i][j], 0, 0, 0);
        __builtin_amdgcn_s_setprio(0);

        if (m < 143) __builtin_amdgcn_s_barrier();
        unsigned tmp = c0B; c0B = c1B; c1B = c2B; c2B = tmp;
    };

#pragma unroll 1
    for (int mo = 0; mo < 144; mo += 2) {     // 9 taps x 16 k-chunks
        chunk_body(mo,     ahP, ahQ);
        chunk_body(mo + 1, ahQ, ahP);
    }

    // epilogue: combine, bias, leaky, split-store. guard ragged pos tile.
#pragma unroll
    for (int i = 0; i < 4; ++i) {
#pragma unroll
        for (int j = 0; j < 4; ++j) {
            int n = co0 + cq * 64 + j * 16 + col;
            float bv = bias[n];
#pragma unroll
            for (int rr = 0; rr < 4; ++rr) {
                int p = p0 + ph * 64 + i * 16 + quad * 4 + rr;
                if (p < NP) {
                    float v = acc1[i][j][rr] * 0.0625f + acc2[i][j][rr] * (1.0f / 32768.0f) + bv;
                    v = v > 0.f ? v : 0.1f * v;
                    _Float16 h = (_Float16)v;
                    _Float16 lo = (_Float16)((v - (float)h) * 2048.0f);
                    size_t o = boff + (size_t)padidx(p) * CH + n;
                    Oh[o] = h; Ol[o] = lo;
                }
            }
        }
    }
}

// ---------------------------------------------------------------------------
// Head: 1x1 convs + decode. One wave per (b,pos); lanes split ci (64x8=512).
// ---------------------------------------------------------------------------
__global__ __launch_bounds__(256)
void head_kernel(const _Float16* __restrict__ Rh, const _Float16* __restrict__ Rl,
                 const _Float16* __restrict__ Ch, const _Float16* __restrict__ Cl,
                 const float* __restrict__ objw, const float* __restrict__ objb,
                 const float* __restrict__ clsw, const float* __restrict__ clsb,
                 const float* __restrict__ regw, const float* __restrict__ regb,
                 float* __restrict__ out) {
    const int wid = (blockIdx.x * 256 + threadIdx.x) >> 6;  // 0..12799
    const int l = threadIdx.x & 63;
    const int b = wid / NP, p = wid - b * NP;
    const size_t base = (size_t)b * (PADN * CH) + (size_t)padidx(p) * CH + l * 8;

    v8h rh = *(const v8h*)(Rh + base), rl = *(const v8h*)(Rl + base);
    v8h ch = *(const v8h*)(Ch + base), cl = *(const v8h*)(Cl + base);
    float rv[8], cv[8];
#pragma unroll
    for (int k = 0; k < 8; ++k) {
        rv[k] = (float)rh[k] + (float)rl[k] * (1.0f / 2048.0f);
        cv[k] = (float)ch[k] + (float)cl[k] * (1.0f / 2048.0f);
    }
    float s[25];
#pragma unroll
    for (int o = 0; o < 25; ++o) s[o] = 0.f;
#pragma unroll
    for (int k = 0; k < 8; ++k) s[0] = fmaf(objw[l * 8 + k], rv[k], s[0]);
#pragma unroll
    for (int c = 0; c < NCLS; ++c)
#pragma unroll
        for (int k = 0; k < 8; ++k) s[1 + c] = fmaf(clsw[c * CH + l * 8 + k], cv[k], s[1 + c]);
#pragma unroll
    for (int q = 0; q < 4; ++q)
#pragma unroll
        for (int k = 0; k < 8; ++k) s[21 + q] = fmaf(regw[q * CH + l * 8 + k], rv[k], s[21 + q]);
#pragma unroll
    for (int o = 0; o < 25; ++o) {
#pragma unroll
        for (int off = 32; off > 0; off >>= 1) s[o] += __shfl_xor(s[o], off);
    }
    if (l == 0) {
        int gp = b * NP + p;
        float obj  = s[0] + objb[0];
        float sobj = 1.f / (1.f + expf(-obj));
        float lg[NCLS];
        float m = -1e30f; int am = 0;
#pragma unroll
        for (int c = 0; c < NCLS; ++c) {
            lg[c] = s[1 + c] + clsb[c];
            if (lg[c] > m) { m = lg[c]; am = c; }
        }
        float se = 0.f;
#pragma unroll
        for (int c = 0; c < NCLS; ++c) se += expf(lg[c] - m);
        float best = sobj / se;

        float r0 = s[21] + regb[0], r1 = s[22] + regb[1];
        float r2 = s[23] + regb[2], r3 = s[24] + regb[3];
        int gy = p / FMPX, gx = p - gy * FMPX;
        float cx = 1.f / (1.f + expf(-r0)) + (float)gx;
        float cy = 1.f / (1.f + expf(-r1)) + (float)gy;
        float hw = 0.5f * expf(r2);
        float hh = 0.5f * expf(r3);
        const float sc = 32.f / 1280.f;
        float x1 = fminf(fmaxf((cx - hw) * sc, 0.f), 1.f);
        float y1 = fminf(fmaxf((cy - hh) * sc, 0.f), 1.f);
        float x2 = fminf(fmaxf((cx + hw) * sc, 0.f), 1.f);
        float y2 = fminf(fmaxf((cy + hh) * sc, 0.f), 1.f);

        ((float4*)out)[gp] = make_float4(x1, y1, x2, y2);
        out[4 * BATCH * NP + gp] = best;
        out[5 * BATCH * NP + gp] = (float)am;
        out[6 * BATCH * NP + gp] = 0.f;
    }
}

// ---------------------------------------------------------------------------
// Sort-based greedy NMS: 1024 thr, MLP kept-scan, shfl resolve. (unchanged)
// ---------------------------------------------------------------------------
__global__ __launch_bounds__(1024)
void nms_kernel(float* __restrict__ out) {
    const int c = blockIdx.x, b = blockIdx.y;
    const int t = threadIdx.x;
    const int w = t >> 6, l = t & 63;

    __shared__ unsigned long long skey[2048];
    __shared__ float4 CBox[NP];
    __shared__ float4 KBox[1664];
    __shared__ unsigned long long wmask[16];
    __shared__ int Kcnt;

    for (int j = t; j < NP; j += 1024) {
        int gp = b * NP + j;
        float4 bx = ((const float4*)out)[gp];
        float best = out[4 * BATCH * NP + gp];
        int   ci   = (int)out[5 * BATCH * NP + gp];
        CBox[j] = bx;
        bool alive = (ci == c) && (best >= CONF_THR);
        unsigned long long key = alive
            ? ~(((unsigned long long)__float_as_uint(best) << 32)
                | (unsigned long long)(0xFFFFFFFFu - (unsigned)j))
            : ~0ull;
        skey[j] = key;
    }
    for (int j = NP + t; j < 2048; j += 1024) skey[j] = ~0ull;
    for (int j = t; j < 1664; j += 1024) KBox[j] = make_float4(0.f, 0.f, 0.f, 0.f);
    if (t == 0) Kcnt = 0;

    for (unsigned k = 2; k <= 2048; k <<= 1) {
        for (unsigned j = k >> 1; j > 0; j >>= 1) {
            __syncthreads();
            for (unsigned i = t; i < 2048; i += 1024) {
                unsigned p = i ^ j;
                if (p > i) {
                    bool up = ((i & k) == 0);
                    unsigned long long a = skey[i], bq = skey[p];
                    if ((a > bq) == up) { skey[i] = bq; skey[p] = a; }
                }
            }
        }
    }
    __syncthreads();

    float* keepout = out + 6 * BATCH * NP + b * NP;
    for (int base = 0; base < NP; base += 64) {
        unsigned long long ik = skey[base + l];
        bool valid = (ik != ~0ull);
        unsigned long long vm = __ballot(valid);
        if (vm == 0) break;

        unsigned idx = 0;
        float4 bx = make_float4(0.f, 0.f, 0.f, 0.f);
        float ar = 0.f;
        if (valid) {
            unsigned long long K = ~ik;
            idx = 0xFFFFFFFFu - (unsigned)(K & 0xFFFFFFFFull);
            bx  = CBox[idx];
            ar  = (bx.z - bx.x) * (bx.w - bx.y);
        }
        int prevK = Kcnt;
        int prevKpad = (prevK + 63) & ~63;

        bool sup = false;
        for (int kk = w * 4; kk < prevKpad; kk += 64) {
            float4 kb0 = KBox[kk],     kb1 = KBox[kk + 1];
            float4 kb2 = KBox[kk + 2], kb3 = KBox[kk + 3];
#pragma unroll
            for (int q = 0; q < 4; ++q) {
                float4 kb = q == 0 ? kb0 : q == 1 ? kb1 : q == 2 ? kb2 : kb3;
                float kar = (kb.z - kb.x) * (kb.w - kb.y);
                float xx1 = fmaxf(kb.x, bx.x);
                float yy1 = fmaxf(kb.y, bx.y);
                float xx2 = fminf(kb.z, bx.z);
                float yy2 = fminf(kb.w, bx.w);
                float ww = fmaxf(1e-28f, xx2 - xx1);
                float hh = fmaxf(1e-28f, yy2 - yy1);
                float inter = ww * hh;
                float iou = inter / (kar + ar - inter + 1e-14f);
                sup |= (iou > NMS_THR);
            }
        }
        wmask[w] = __ballot(valid && !sup);
        __syncthreads();

        if (w == 0) {
            unsigned long long alive = wmask[0];
#pragma unroll
            for (int q = 1; q < 16; ++q) alive &= wmask[q];
            unsigned long long smask = 0;
            for (int s = 0; s < 63; ++s) {
                float ox1 = __shfl(bx.x, s), oy1 = __shfl(bx.y, s);
                float ox2 = __shfl(bx.z, s), oy2 = __shfl(bx.w, s);
                float oar = (ox2 - ox1) * (oy2 - oy1);
                float xx1 = fmaxf(ox1, bx.x);
                float yy1 = fmaxf(oy1, bx.y);
                float xx2 = fminf(ox2, bx.z);
                float yy2 = fminf(oy2, bx.w);
                float ww = fmaxf(1e-28f, xx2 - xx1);
                float hh = fmaxf(1e-28f, yy2 - yy1);
                float inter = ww * hh;
                float iou = inter / (oar + ar - inter + 1e-14f);
                if (s < l && iou > NMS_THR) smask |= (1ull << s);
            }
            unsigned long long kept = 0;
            while (alive) {
                int s = __builtin_ctzll(alive);
                kept |= (1ull << s);
                alive &= ~(1ull << s);
                unsigned long long dead = __ballot((smask >> s) & 1ull);
                alive &= ~dead;
            }
            if ((kept >> l) & 1ull) {
                int pos = prevK + __builtin_popcountll(kept & ((1ull << l) - 1ull));
                KBox[pos] = bx;
                keepout[idx] = 1.0f;
            }
            if (l == 0) Kcnt = prevK + __builtin_popcountll(kept);
        }
        __syncthreads();
    }
}

// ---------------------------------------------------------------------------
extern "C" void kernel_launch(void* const* d_in, const int* in_sizes, int n_in,
                              void* d_out, int out_size, void* d_ws, size_t ws_size,
                              hipStream_t stream) {
    const float* x      = (const float*)d_in[0];
    const float* cls_w  = (const float*)d_in[1];
    const float* cls_b  = (const float*)d_in[2];
    const float* reg_w  = (const float*)d_in[3];
    const float* reg_b  = (const float*)d_in[4];
    const float* obj_w  = (const float*)d_in[5];
    const float* obj_b  = (const float*)d_in[6];
    const float* clsp_w = (const float*)d_in[7];
    const float* clsp_b = (const float*)d_in[8];
    const float* regp_w = (const float*)d_in[9];
    const float* regp_b = (const float*)d_in[10];
    float* out = (float*)d_out;

    _Float16* ws = (_Float16*)d_ws;
    _Float16* Xh = ws;                     // pair 0
    _Float16* Xl = ws + FPLANE;
    _Float16* Ah = ws + 2 * FPLANE;        // pair 1
    _Float16* Al = ws + 3 * FPLANE;
    _Float16* Bh = ws + 4 * FPLANE;        // pair 2
    _Float16* Bl = ws + 5 * FPLANE;
    _Float16* Ch = ws + 6 * FPLANE;        // pair 3
    _Float16* Cl = ws + 7 * FPLANE;
    _Float16* W0h = ws + 8 * FPLANE;       // weight set 0
    _Float16* W0l = W0h + WSZ;
    _Float16* W1h = W0l + WSZ;             // weight set 1
    _Float16* W1l = W1h + WSZ;
    const size_t LW = (size_t)CH * CH * 9;

    border_zero<<<dim3(2624), 256, 0, stream>>>((uint4*)d_ws);
    xprep_kernel<<<dim3(25, 8, 8), 256, 0, stream>>>(x, Xh, Xl);

    dim3 wgrid(16, 16), blk(256);

    // D1: cls1 (X->A) || reg1 (X->C)
    wtrans_kernel<<<wgrid, blk, 0, stream>>>(cls_w, W0h, W0l);
    wtrans_kernel<<<wgrid, blk, 0, stream>>>(reg_w, W1h, W1l);
    conv_dual<<<dim3(416), 512, 0, stream>>>(Xh, Xl, W0h, W0l, cls_b,      Ah, Al,
                                             Xh, Xl, W1h, W1l, reg_b,      Ch, Cl);
    // D2: cls2 (A->B) || reg2 (C->X)
    wtrans_kernel<<<wgrid, blk, 0, stream>>>(cls_w + LW, W0h, W0l);
    wtrans_kernel<<<wgrid, blk, 0, stream>>>(reg_w + LW, W1h, W1l);
    conv_dual<<<dim3(416), 512, 0, stream>>>(Ah, Al, W0h, W0l, cls_b + CH, Bh, Bl,
                                             Ch, Cl, W1h, W1l, reg_b + CH, Xh, Xl);
    // D3: reg3 (X->C)
    wtrans_kernel<<<wgrid, blk, 0, stream>>>(reg_w + 2 * LW, W0h, W0l);
    conv_dual<<<dim3(208), 512, 0, stream>>>(Xh, Xl, W0h, W0l, reg_b + 2 * CH, Ch, Cl,
                                             Xh, Xl, W0h, W0l, reg_b + 2 * CH, Ch, Cl);
    // D4: reg4 (C->X)
    wtrans_kernel<<<wgrid, blk, 0, stream>>>(reg_w + 3 * LW, W0h, W0l);
    conv_dual<<<dim3(208), 512, 0, stream>>>(Ch, Cl, W0h, W0l, reg_b + 3 * CH, Xh, Xl,
                                             Ch, Cl, W0h, W0l, reg_b + 3 * CH, Xh, Xl);

    head_kernel<<<dim3(3200), 256, 0, stream>>>(Xh, Xl, Bh, Bl, obj_w, obj_b,
                                                clsp_w, clsp_b, regp_w, regp_b, out);
    nms_kernel<<<dim3(NCLS, BATCH), 1024, 0, stream>>>(out);
}

// Round 7
// 1922.880 us; speedup vs baseline: 1.4985x; 1.4985x over previous
//
#include <hip/hip_runtime.h>
#include <math.h>

#define CH    512
#define FMPX  40
#define PW    42            // padded row width
#define PADN  1764          // 42*42
#define NP    1600          // 40*40
#define BATCH 8
#define NCLS  20
#define CONF_THR 0.001f
#define NMS_THR  0.6f

typedef _Float16 v8h __attribute__((ext_vector_type(8)));
typedef float    v4f __attribute__((ext_vector_type(4)));

// ws layout (in _Float16 units): 8 feature planes (4 hi/lo pairs: X,A,B,C),
// then 2 transposed-weight sets (hi/lo each).  Total 134.5 MB.
#define FPLANE  ((size_t)BATCH * PADN * CH)          // 7,225,344 halves
#define WSZ     ((size_t)9 * CH * CH)                // 2,359,296 halves

__device__ __forceinline__ int padidx(int p) { return p + 2 * (p / FMPX) + PW + 1; }

// async global->LDS, 16 B per lane
typedef __attribute__((address_space(1))) const void* gas_t;
typedef __attribute__((address_space(3))) void*       las_t;
__device__ __forceinline__ void gl2lds16(const void* g, void* l) {
    __builtin_amdgcn_global_load_lds((gas_t)g, (las_t)l, 16, 0, 0);
}
// raw LDS byte address of a generic pointer into __shared__
__device__ __forceinline__ unsigned lds_addr(void* p) {
    return (unsigned)(uintptr_t)(las_t)p;
}
// inline-asm ds_read_b128: invisible to SIInsertWaitcnts' LDS-DMA alias
// tracking, so no spurious vmcnt/lgkm drains around the manual schedule.
__device__ __forceinline__ v8h lds_b128(unsigned a) {
    v8h r;
    asm volatile("ds_read_b128 %0, %1" : "=v"(r) : "v"(a));
    return r;
}

// ---------------------------------------------------------------------------
// Zero the padded borders of all 8 feature planes (ws re-poisoned each call).
// ---------------------------------------------------------------------------
__global__ __launch_bounds__(256)
void border_zero(uint4* __restrict__ ws) {
    int idx = blockIdx.x * 256 + threadIdx.x;
    int u    = idx & 63;
    int cell = (idx >> 6) % 164;
    int b    = (idx / (64 * 164)) & 7;
    int pl   = idx / (64 * 164 * 8);          // 0..7
    int pi;
    if (cell < 42)      pi = cell;
    else if (cell < 84) pi = 41 * PW + (cell - 42);
    else { int r = cell - 84; pi = (1 + (r >> 1)) * PW + ((r & 1) ? 41 : 0); }
    size_t hoff = (size_t)pl * FPLANE + (size_t)b * (PADN * CH) + (size_t)pi * CH;
    ws[(hoff >> 3) + u] = make_uint4(0u, 0u, 0u, 0u);
}

// ---------------------------------------------------------------------------
// x [b][512][1600] fp32 -> padded pos-major fp16 hi/lo planes [b][1764][512].
// ---------------------------------------------------------------------------
__global__ __launch_bounds__(256)
void xprep_kernel(const float* __restrict__ x, _Float16* __restrict__ Xh,
                  _Float16* __restrict__ Xl) {
    __shared__ float T[64][65];
    const int t = threadIdx.x;
    const int p0  = blockIdx.x * 64;   // 25
    const int ci0 = blockIdx.y * 64;   // 8
    const int b   = blockIdx.z;        // 8
#pragma unroll
    for (int it = 0; it < 16; ++it) {
        int row = (t >> 6) + 4 * it;
        int col = t & 63;
        T[col][row] = x[((size_t)b * CH + ci0 + row) * NP + p0 + col];
    }
    __syncthreads();
#pragma unroll
    for (int it = 0; it < 16; ++it) {
        int posl = (t >> 6) + 4 * it;
        int ci   = t & 63;
        float v = T[posl][ci];
        _Float16 h = (_Float16)v;
        _Float16 l = (_Float16)((v - (float)h) * 2048.0f);
        size_t o = (size_t)b * (PADN * CH) + (size_t)padidx(p0 + posl) * CH + ci0 + ci;
        Xh[o] = h; Xl[o] = l;
    }
}

// ---------------------------------------------------------------------------
// w [co][ci][3][3] fp32 -> Wh/Wl [tap][co][ci] fp16.
// ---------------------------------------------------------------------------
__global__ __launch_bounds__(256)
void wtrans_kernel(const float* __restrict__ w, _Float16* __restrict__ Wh,
                   _Float16* __restrict__ Wl) {
    __shared__ float tile[32][289];
    const int t = threadIdx.x;
    const int co0 = blockIdx.x * 32;   // 16
    const int ci0 = blockIdx.y * 32;   // 16
#pragma unroll
    for (int g = 0; g < 36; ++g) {     // 32*288 = 9216
        int l = t + 256 * g;
        int co = l / 288, j = l - co * 288;
        tile[co][j] = w[(size_t)(co0 + co) * 4608 + ci0 * 9 + j];
    }
    __syncthreads();
#pragma unroll
    for (int tap = 0; tap < 9; ++tap) {
#pragma unroll
        for (int cg = 0; cg < 4; ++cg) {
            int co = cg * 8 + (t >> 5);
            int ci = t & 31;
            float v = tile[co][ci * 9 + tap];
            _Float16 h = (_Float16)(16.0f * v);
            _Float16 l = (_Float16)((v - (float)h * 0.0625f) * 32768.0f);
            size_t o = ((size_t)tap * CH + co0 + co) * CH + ci0 + ci;
            Wh[o] = h; Wl[o] = l;
        }
    }
}

// ---------------------------------------------------------------------------
// Dual 3x3 conv via MFMA, split-fp16.  r2 geometry (proven staging):
//   block = 512 thr / 8 waves, tile 128pos x 256co, wave tile 64pos x 64co,
//   BK=32 chunk = 48 KB, THREE LDS buffers (144 KB), gl2lds staging.
// ROUND-7: CROSS-CHUNK FRAGMENT PREFETCH.  r2's 4017 cyc/chunk = LDS-port
// burst (~2100) + MFMA (1862) in strict alternation (all 8 waves lockstep).
// Fix: stage(m+2) at chunk TOP (full chunk of slack -> end-of-chunk vmcnt(0)
// is free AND buffer m+1 is complete BEFORE chunk m starts), so chunk m+1's
// fragments are ds_read DURING chunk m's MFMA clusters:
//   - ah: ping-pong regs (ah(m+1) read after acc1 cluster)
//   - al: read at chunk top from buffer m; arrives under acc1's shadow
//   - bh/bl: rolling per-j replacement after each acc2 pair's last use
// Frag regs ~80 VGPR + misc ~35 + acc 128 AGPR = fits 256/wave at 8 waves.
// Per-element MFMA order identical to r2 (acc1: ah*bh once; acc2: ah*bl then
// al*bh; i ascending) -> bit-identical output.
// Buffers at chunk m: c0 = m (al source), c1 = m+1 (frag prefetch source),
// c2 = stage(m+2) target.  Rotation c0<-c1<-c2<-c0 each chunk.
// lgkm FIFO: top wait lgkmcnt(4) keeps al in flight; mid wait lgkmcnt(4)
// forces al, keeps ah(m+1).  sched_barrier(0) after waits (rule 18) and
// after each pair (pins rolling reads below their pair's MFMAs).
// Block decode (1D grid, nconv*208 blocks):
//   b = bid & 7 (XCD swizzle); q = bid >> 3; cid = q/26; r = q%26;
//   cos = r & 1; pt = r >> 1 (0..12); 13th pos tile ragged (guarded store)
// Per-buffer halves: Ah[0,4096) Al[4096,8192) Bh[8192,16384) Bl[16384,24576)
// ---------------------------------------------------------------------------
__global__ __launch_bounds__(512, 2)
void conv_dual(const _Float16* __restrict__ I0h, const _Float16* __restrict__ I0l,
               const _Float16* __restrict__ W0h, const _Float16* __restrict__ W0l,
               const float* __restrict__ bias0,
               _Float16* __restrict__ O0h, _Float16* __restrict__ O0l,
               const _Float16* __restrict__ I1h, const _Float16* __restrict__ I1l,
               const _Float16* __restrict__ W1h, const _Float16* __restrict__ W1l,
               const float* __restrict__ bias1,
               _Float16* __restrict__ O1h, _Float16* __restrict__ O1l) {
    __shared__ _Float16 sm[73728];   // 3 x 24576 halves = 144 KB
    const int t = threadIdx.x;
    const int w = t >> 6, l = t & 63;
    const int quad = l >> 4, col = l & 15;
    const int ph = w >> 2, cq = w & 3;          // wave's pos-half / co-quad

    const int bid = blockIdx.x;
    const int b   = bid & 7;
    const int q   = bid >> 3;
    const int cid = q / 26;
    const int r   = q - 26 * cid;
    const int co0 = (r & 1) * 256;
    const int p0  = (r >> 1) * 128;

    const _Float16* Ih = cid ? I1h : I0h;
    const _Float16* Il = cid ? I1l : I0l;
    const _Float16* Wh = cid ? W1h : W0h;
    const _Float16* Wl = cid ? W1l : W0l;
    const float*  bias = cid ? bias1 : bias0;
    _Float16* Oh = cid ? O1h : O0h;
    _Float16* Ol = cid ? O1l : O0l;

    const size_t boff = (size_t)b * (PADN * CH);

    // staging source bases (halves)
    const size_t sA  = boff + (size_t)padidx(p0 + 16 * w + col) * CH + quad * 8;
    const size_t sB0 = (size_t)(co0 + 32 * w + col) * CH + quad * 8;
    // staging dests within a buffer (halves)
    const int dA = w * 512 + l * 8;                    // A-hi; A-lo at +4096
    const int dB = 8192 + (2 * w) * 512 + l * 8;       // B-hi; B-lo at +8192

    // fragment read byte-addresses (buffer 0); + buffer byte offset selects
    const unsigned smB = lds_addr(sm);
    unsigned aRh[4], aRl[4], bRh[4], bRl[4];
#pragma unroll
    for (int i = 0; i < 4; ++i) {
        aRh[i] = smB + (ph * 4 + i) * 1024 + l * 16;
        aRl[i] = aRh[i] + 8192;
    }
#pragma unroll
    for (int j = 0; j < 4; ++j) {
        bRh[j] = smB + 16384 + (cq * 4 + j) * 1024 + l * 16;
        bRl[j] = bRh[j] + 16384;
    }

    // staging pointer state (points at chunk to be staged next)
    const _Float16 *pAh, *pAl, *pWh, *pWl;
    auto set_stage = [&](int ms) {
        const int tap = ms >> 4, cc = (ms & 15) << 5;
        const int ty  = tap / 3;
        const int tsh = ((ty - 1) * PW + (tap - ty * 3 - 1)) * CH + cc;
        const size_t wo = (size_t)tap * (CH * CH) + cc;
        pAh = Ih + sA + tsh;  pAl = Il + sA + tsh;
        pWh = Wh + wo + sB0;  pWl = Wl + wo + sB0;
    };
    auto stage6 = [&](unsigned nH) {                  // 6 vm ops
        _Float16* dst = sm + nH;
        gl2lds16(pAh,           dst + dA);
        gl2lds16(pAl,           dst + 4096 + dA);
        gl2lds16(pWh,           dst + dB);
        gl2lds16(pWh + 16 * CH, dst + dB + 512);
        gl2lds16(pWl,           dst + 8192 + dB);
        gl2lds16(pWl + 16 * CH, dst + 8192 + dB + 512);
    };

    v4f acc1[4][4], acc2[4][4];
#pragma unroll
    for (int i = 0; i < 4; ++i)
#pragma unroll
        for (int j = 0; j < 4; ++j) {
            acc1[i][j] = (v4f){0.f, 0.f, 0.f, 0.f};
            acc2[i][j] = (v4f){0.f, 0.f, 0.f, 0.f};
        }

    unsigned c0H = 0, c1H = 24576, c2H = 49152;   // al-src / prefetch-src / stage

    // prologue: stage chunks 0,1; full drain; pre-read chunk-0 ah/bh/bl
    set_stage(0); stage6(0);
    set_stage(1); stage6(24576);
    set_stage(2);
    asm volatile("s_waitcnt vmcnt(0)" ::: "memory");
    __builtin_amdgcn_s_barrier();

    v8h ahA[4], ahB[4], al[4], bh[4], bl[4];
#pragma unroll
    for (int i = 0; i < 4; ++i) ahA[i] = lds_b128(aRh[i]);
#pragma unroll
    for (int j = 0; j < 4; ++j) { bh[j] = lds_b128(bRh[j]); bl[j] = lds_b128(bRl[j]); }

    // one chunk: consume ah (cur), prefetch ahN (chunk m+1); al/bh/bl rolling
    auto chunk_body = [&](int m, v8h (&ah)[4], v8h (&ahN)[4]) {
        const unsigned b0 = c0H * 2;          // chunk m buffer, bytes
        const unsigned b1 = c1H * 2;          // chunk m+1 buffer, bytes

        // 1. al(m) reads from buffer m (arrive under acc1's shadow)  [4 lgkm]
        al[0] = lds_b128(aRl[0] + b0);
        al[1] = lds_b128(aRl[1] + b0);
        al[2] = lds_b128(aRl[2] + b0);
        al[3] = lds_b128(aRl[3] + b0);

        // 2. stage(m+2) at chunk top -> full chunk of slack   [6 vm]
        if (m < 142) {
            stage6(c2H);
            const int nx = m + 3;
            if (nx < 144) {
                if ((nx & 15) == 0) set_stage(nx);
                else { pAh += 32; pAl += 32; pWh += 32; pWl += 32; }
            }
        }

        // 3. force ah/bh/bl(m) (all older than al); al keeps flying
        asm volatile("s_waitcnt lgkmcnt(4)" ::: "memory");
        __builtin_amdgcn_sched_barrier(0);
        __builtin_amdgcn_s_setprio(1);
        // cluster acc1: ah*bh, j ascending (16 MFMA)
#pragma unroll
        for (int i = 0; i < 4; ++i)
            acc1[i][0] = __builtin_amdgcn_mfma_f32_16x16x32_f16(ah[i], bh[0], acc1[i][0], 0, 0, 0);
#pragma unroll
        for (int i = 0; i < 4; ++i)
            acc1[i][1] = __builtin_amdgcn_mfma_f32_16x16x32_f16(ah[i], bh[1], acc1[i][1], 0, 0, 0);
#pragma unroll
        for (int i = 0; i < 4; ++i)
            acc1[i][2] = __builtin_amdgcn_mfma_f32_16x16x32_f16(ah[i], bh[2], acc1[i][2], 0, 0, 0);
#pragma unroll
        for (int i = 0; i < 4; ++i)
            acc1[i][3] = __builtin_amdgcn_mfma_f32_16x16x32_f16(ah[i], bh[3], acc1[i][3], 0, 0, 0);
        __builtin_amdgcn_s_setprio(0);
        __builtin_amdgcn_sched_barrier(0);

        // 4. prefetch ah(m+1) into ping-pong set            [4 lgkm]
        if (m < 143) {
            ahN[0] = lds_b128(aRh[0] + b1);
            ahN[1] = lds_b128(aRh[1] + b1);
            ahN[2] = lds_b128(aRh[2] + b1);
            ahN[3] = lds_b128(aRh[3] + b1);
        }

        // 5. force al(m); ah(m+1) keeps flying
        if (m < 143) { asm volatile("s_waitcnt lgkmcnt(4)" ::: "memory"); }
        else         { asm volatile("s_waitcnt lgkmcnt(0)" ::: "memory"); }
        __builtin_amdgcn_sched_barrier(0);

        // 6. acc2 pairs j=0..3: ah*bl[j] then al*bh[j]; then roll bh/bl[j]
#pragma unroll
        for (int j = 0; j < 4; ++j) {
            __builtin_amdgcn_s_setprio(1);
#pragma unroll
            for (int i = 0; i < 4; ++i)
                acc2[i][j] = __builtin_amdgcn_mfma_f32_16x16x32_f16(ah[i], bl[j], acc2[i][j], 0, 0, 0);
#pragma unroll
            for (int i = 0; i < 4; ++i)
                acc2[i][j] = __builtin_amdgcn_mfma_f32_16x16x32_f16(al[i], bh[j], acc2[i][j], 0, 0, 0);
            __builtin_amdgcn_s_setprio(0);
            __builtin_amdgcn_sched_barrier(0);   // pin rolling reads below pair
            if (m < 143) {
                bh[j] = lds_b128(bRh[j] + b1);   // chunk m+1 B frags  [2 lgkm]
                bl[j] = lds_b128(bRl[j] + b1);
            }
        }

        // 7. end: force stage(m+2) (issued a full chunk ago -> cheap); barrier
        if (m < 143) {
            asm volatile("s_waitcnt vmcnt(0)" ::: "memory");
            __builtin_amdgcn_s_barrier();
        }
        unsigned tmp = c0H; c0H = c1H; c1H = c2H; c2H = tmp;
    };

#pragma unroll 1
    for (int mo = 0; mo < 144; mo += 2) {     // 9 taps x 16 k-chunks
        chunk_body(mo,     ahA, ahB);
        chunk_body(mo + 1, ahB, ahA);
    }

    // epilogue: combine, bias, leaky, split-store. guard ragged pos tile.
#pragma unroll
    for (int i = 0; i < 4; ++i) {
#pragma unroll
        for (int j = 0; j < 4; ++j) {
            int n = co0 + cq * 64 + j * 16 + col;
            float bv = bias[n];
#pragma unroll
            for (int rr = 0; rr < 4; ++rr) {
                int p = p0 + ph * 64 + i * 16 + quad * 4 + rr;
                if (p < NP) {
                    float v = acc1[i][j][rr] * 0.0625f + acc2[i][j][rr] * (1.0f / 32768.0f) + bv;
                    v = v > 0.f ? v : 0.1f * v;
                    _Float16 h = (_Float16)v;
                    _Float16 lo = (_Float16)((v - (float)h) * 2048.0f);
                    size_t o = boff + (size_t)padidx(p) * CH + n;
                    Oh[o] = h; Ol[o] = lo;
                }
            }
        }
    }
}

// ---------------------------------------------------------------------------
// Head: 1x1 convs + decode. One wave per (b,pos); lanes split ci (64x8=512).
// ---------------------------------------------------------------------------
__global__ __launch_bounds__(256)
void head_kernel(const _Float16* __restrict__ Rh, const _Float16* __restrict__ Rl,
                 const _Float16* __restrict__ Ch, const _Float16* __restrict__ Cl,
                 const float* __restrict__ objw, const float* __restrict__ objb,
                 const float* __restrict__ clsw, const float* __restrict__ clsb,
                 const float* __restrict__ regw, const float* __restrict__ regb,
                 float* __restrict__ out) {
    const int wid = (blockIdx.x * 256 + threadIdx.x) >> 6;  // 0..12799
    const int l = threadIdx.x & 63;
    const int b = wid / NP, p = wid - b * NP;
    const size_t base = (size_t)b * (PADN * CH) + (size_t)padidx(p) * CH + l * 8;

    v8h rh = *(const v8h*)(Rh + base), rl = *(const v8h*)(Rl + base);
    v8h ch = *(const v8h*)(Ch + base), cl = *(const v8h*)(Cl + base);
    float rv[8], cv[8];
#pragma unroll
    for (int k = 0; k < 8; ++k) {
        rv[k] = (float)rh[k] + (float)rl[k] * (1.0f / 2048.0f);
        cv[k] = (float)ch[k] + (float)cl[k] * (1.0f / 2048.0f);
    }
    float s[25];
#pragma unroll
    for (int o = 0; o < 25; ++o) s[o] = 0.f;
#pragma unroll
    for (int k = 0; k < 8; ++k) s[0] = fmaf(objw[l * 8 + k], rv[k], s[0]);
#pragma unroll
    for (int c = 0; c < NCLS; ++c)
#pragma unroll
        for (int k = 0; k < 8; ++k) s[1 + c] = fmaf(clsw[c * CH + l * 8 + k], cv[k], s[1 + c]);
#pragma unroll
    for (int q = 0; q < 4; ++q)
#pragma unroll
        for (int k = 0; k < 8; ++k) s[21 + q] = fmaf(regw[q * CH + l * 8 + k], rv[k], s[21 + q]);
#pragma unroll
    for (int o = 0; o < 25; ++o) {
#pragma unroll
        for (int off = 32; off > 0; off >>= 1) s[o] += __shfl_xor(s[o], off);
    }
    if (l == 0) {
        int gp = b * NP + p;
        float obj  = s[0] + objb[0];
        float sobj = 1.f / (1.f + expf(-obj));
        float lg[NCLS];
        float m = -1e30f; int am = 0;
#pragma unroll
        for (int c = 0; c < NCLS; ++c) {
            lg[c] = s[1 + c] + clsb[c];
            if (lg[c] > m) { m = lg[c]; am = c; }
        }
        float se = 0.f;
#pragma unroll
        for (int c = 0; c < NCLS; ++c) se += expf(lg[c] - m);
        float best = sobj / se;

        float r0 = s[21] + regb[0], r1 = s[22] + regb[1];
        float r2 = s[23] + regb[2], r3 = s[24] + regb[3];
        int gy = p / FMPX, gx = p - gy * FMPX;
        float cx = 1.f / (1.f + expf(-r0)) + (float)gx;
        float cy = 1.f / (1.f + expf(-r1)) + (float)gy;
        float hw = 0.5f * expf(r2);
        float hh = 0.5f * expf(r3);
        const float sc = 32.f / 1280.f;
        float x1 = fminf(fmaxf((cx - hw) * sc, 0.f), 1.f);
        float y1 = fminf(fmaxf((cy - hh) * sc, 0.f), 1.f);
        float x2 = fminf(fmaxf((cx + hw) * sc, 0.f), 1.f);
        float y2 = fminf(fmaxf((cy + hh) * sc, 0.f), 1.f);

        ((float4*)out)[gp] = make_float4(x1, y1, x2, y2);
        out[4 * BATCH * NP + gp] = best;
        out[5 * BATCH * NP + gp] = (float)am;
        out[6 * BATCH * NP + gp] = 0.f;
    }
}

// ---------------------------------------------------------------------------
// Sort-based greedy NMS: 1024 thr, MLP kept-scan, shfl resolve. (unchanged)
// ---------------------------------------------------------------------------
__global__ __launch_bounds__(1024)
void nms_kernel(float* __restrict__ out) {
    const int c = blockIdx.x, b = blockIdx.y;
    const int t = threadIdx.x;
    const int w = t >> 6, l = t & 63;

    __shared__ unsigned long long skey[2048];
    __shared__ float4 CBox[NP];
    __shared__ float4 KBox[1664];
    __shared__ unsigned long long wmask[16];
    __shared__ int Kcnt;

    for (int j = t; j < NP; j += 1024) {
        int gp = b * NP + j;
        float4 bx = ((const float4*)out)[gp];
        float best = out[4 * BATCH * NP + gp];
        int   ci   = (int)out[5 * BATCH * NP + gp];
        CBox[j] = bx;
        bool alive = (ci == c) && (best >= CONF_THR);
        unsigned long long key = alive
            ? ~(((unsigned long long)__float_as_uint(best) << 32)
                | (unsigned long long)(0xFFFFFFFFu - (unsigned)j))
            : ~0ull;
        skey[j] = key;
    }
    for (int j = NP + t; j < 2048; j += 1024) skey[j] = ~0ull;
    for (int j = t; j < 1664; j += 1024) KBox[j] = make_float4(0.f, 0.f, 0.f, 0.f);
    if (t == 0) Kcnt = 0;

    for (unsigned k = 2; k <= 2048; k <<= 1) {
        for (unsigned j = k >> 1; j > 0; j >>= 1) {
            __syncthreads();
            for (unsigned i = t; i < 2048; i += 1024) {
                unsigned p = i ^ j;
                if (p > i) {
                    bool up = ((i & k) == 0);
                    unsigned long long a = skey[i], bq = skey[p];
                    if ((a > bq) == up) { skey[i] = bq; skey[p] = a; }
                }
            }
        }
    }
    __syncthreads();

    float* keepout = out + 6 * BATCH * NP + b * NP;
    for (int base = 0; base < NP; base += 64) {
        unsigned long long ik = skey[base + l];
        bool valid = (ik != ~0ull);
        unsigned long long vm = __ballot(valid);
        if (vm == 0) break;

        unsigned idx = 0;
        float4 bx = make_float4(0.f, 0.f, 0.f, 0.f);
        float ar = 0.f;
        if (valid) {
            unsigned long long K = ~ik;
            idx = 0xFFFFFFFFu - (unsigned)(K & 0xFFFFFFFFull);
            bx  = CBox[idx];
            ar  = (bx.z - bx.x) * (bx.w - bx.y);
        }
        int prevK = Kcnt;
        int prevKpad = (prevK + 63) & ~63;

        bool sup = false;
        for (int kk = w * 4; kk < prevKpad; kk += 64) {
            float4 kb0 = KBox[kk],     kb1 = KBox[kk + 1];
            float4 kb2 = KBox[kk + 2], kb3 = KBox[kk + 3];
#pragma unroll
            for (int q = 0; q < 4; ++q) {
                float4 kb = q == 0 ? kb0 : q == 1 ? kb1 : q == 2 ? kb2 : kb3;
                float kar = (kb.z - kb.x) * (kb.w - kb.y);
                float xx1 = fmaxf(kb.x, bx.x);
                float yy1 = fmaxf(kb.y, bx.y);
                float xx2 = fminf(kb.z, bx.z);
                float yy2 = fminf(kb.w, bx.w);
                float ww = fmaxf(1e-28f, xx2 - xx1);
                float hh = fmaxf(1e-28f, yy2 - yy1);
                float inter = ww * hh;
                float iou = inter / (kar + ar - inter + 1e-14f);
                sup |= (iou > NMS_THR);
            }
        }
        wmask[w] = __ballot(valid && !sup);
        __syncthreads();

        if (w == 0) {
            unsigned long long alive = wmask[0];
#pragma unroll
            for (int q = 1; q < 16; ++q) alive &= wmask[q];
            unsigned long long smask = 0;
            for (int s = 0; s < 63; ++s) {
                float ox1 = __shfl(bx.x, s), oy1 = __shfl(bx.y, s);
                float ox2 = __shfl(bx.z, s), oy2 = __shfl(bx.w, s);
                float oar = (ox2 - ox1) * (oy2 - oy1);
                float xx1 = fmaxf(ox1, bx.x);
                float yy1 = fmaxf(oy1, bx.y);
                float xx2 = fminf(ox2, bx.z);
                float yy2 = fminf(oy2, bx.w);
                float ww = fmaxf(1e-28f, xx2 - xx1);
                float hh = fmaxf(1e-28f, yy2 - yy1);
                float inter = ww * hh;
                float iou = inter / (oar + ar - inter + 1e-14f);
                if (s < l && iou > NMS_THR) smask |= (1ull << s);
            }
            unsigned long long kept = 0;
            while (alive) {
                int s = __builtin_ctzll(alive);
                kept |= (1ull << s);
                alive &= ~(1ull << s);
                unsigned long long dead = __ballot((smask >> s) & 1ull);
                alive &= ~dead;
            }
            if ((kept >> l) & 1ull) {
                int pos = prevK + __builtin_popcountll(kept & ((1ull << l) - 1ull));
                KBox[pos] = bx;
                keepout[idx] = 1.0f;
            }
            if (l == 0) Kcnt = prevK + __builtin_popcountll(kept);
        }
        __syncthreads();
    }
}

// ---------------------------------------------------------------------------
extern "C" void kernel_launch(void* const* d_in, const int* in_sizes, int n_in,
                              void* d_out, int out_size, void* d_ws, size_t ws_size,
                              hipStream_t stream) {
    const float* x      = (const float*)d_in[0];
    const float* cls_w  = (const float*)d_in[1];
    const float* cls_b  = (const float*)d_in[2];
    const float* reg_w  = (const float*)d_in[3];
    const float* reg_b  = (const float*)d_in[4];
    const float* obj_w  = (const float*)d_in[5];
    const float* obj_b  = (const float*)d_in[6];
    const float* clsp_w = (const float*)d_in[7];
    const float* clsp_b = (const float*)d_in[8];
    const float* regp_w = (const float*)d_in[9];
    const float* regp_b = (const float*)d_in[10];
    float* out = (float*)d_out;

    _Float16* ws = (_Float16*)d_ws;
    _Float16* Xh = ws;                     // pair 0
    _Float16* Xl = ws + FPLANE;
    _Float16* Ah = ws + 2 * FPLANE;        // pair 1
    _Float16* Al = ws + 3 * FPLANE;
    _Float16* Bh = ws + 4 * FPLANE;        // pair 2
    _Float16* Bl = ws + 5 * FPLANE;
    _Float16* Ch = ws + 6 * FPLANE;        // pair 3
    _Float16* Cl = ws + 7 * FPLANE;
    _Float16* W0h = ws + 8 * FPLANE;       // weight set 0
    _Float16* W0l = W0h + WSZ;
    _Float16* W1h = W0l + WSZ;             // weight set 1
    _Float16* W1l = W1h + WSZ;
    const size_t LW = (size_t)CH * CH * 9;

    border_zero<<<dim3(2624), 256, 0, stream>>>((uint4*)d_ws);
    xprep_kernel<<<dim3(25, 8, 8), 256, 0, stream>>>(x, Xh, Xl);

    dim3 wgrid(16, 16), blk(256);

    // D1: cls1 (X->A) || reg1 (X->C)
    wtrans_kernel<<<wgrid, blk, 0, stream>>>(cls_w, W0h, W0l);
    wtrans_kernel<<<wgrid, blk, 0, stream>>>(reg_w, W1h, W1l);
    conv_dual<<<dim3(416), 512, 0, stream>>>(Xh, Xl, W0h, W0l, cls_b,      Ah, Al,
                                             Xh, Xl, W1h, W1l, reg_b,      Ch, Cl);
    // D2: cls2 (A->B) || reg2 (C->X)
    wtrans_kernel<<<wgrid, blk, 0, stream>>>(cls_w + LW, W0h, W0l);
    wtrans_kernel<<<wgrid, blk, 0, stream>>>(reg_w + LW, W1h, W1l);
    conv_dual<<<dim3(416), 512, 0, stream>>>(Ah, Al, W0h, W0l, cls_b + CH, Bh, Bl,
                                             Ch, Cl, W1h, W1l, reg_b + CH, Xh, Xl);
    // D3: reg3 (X->C)
    wtrans_kernel<<<wgrid, blk, 0, stream>>>(reg_w + 2 * LW, W0h, W0l);
    conv_dual<<<dim3(208), 512, 0, stream>>>(Xh, Xl, W0h, W0l, reg_b + 2 * CH, Ch, Cl,
                                             Xh, Xl, W0h, W0l, reg_b + 2 * CH, Ch, Cl);
    // D4: reg4 (C->X)
    wtrans_kernel<<<wgrid, blk, 0, stream>>>(reg_w + 3 * LW, W0h, W0l);
    conv_dual<<<dim3(208), 512, 0, stream>>>(Ch, Cl, W0h, W0l, reg_b + 3 * CH, Xh, Xl,
                                             Ch, Cl, W0h, W0l, reg_b + 3 * CH, Xh, Xl);

    head_kernel<<<dim3(3200), 256, 0, stream>>>(Xh, Xl, Bh, Bl, obj_w, obj_b,
                                                clsp_w, clsp_b, regp_w, regp_b, out);
    nms_kernel<<<dim3(NCLS, BATCH), 1024, 0, stream>>>(out);
}

// Round 8
// 1732.528 us; speedup vs baseline: 1.6632x; 1.1099x over previous
//
#include <hip/hip_runtime.h>
#include <math.h>

#define CH    512
#define FMPX  40
#define PW    42            // padded row width
#define PADN  1764          // 42*42
#define NP    1600          // 40*40
#define BATCH 8
#define NCLS  20
#define CONF_THR 0.001f
#define NMS_THR  0.6f

typedef _Float16 v8h __attribute__((ext_vector_type(8)));
typedef float    v4f __attribute__((ext_vector_type(4)));

// ws layout (in _Float16 units): 8 feature planes (4 hi/lo pairs: X,A,B,C),
// then 2 transposed-weight sets (hi/lo each).  Total 134.5 MB.
#define FPLANE  ((size_t)BATCH * PADN * CH)          // 7,225,344 halves
#define WSZ     ((size_t)9 * CH * CH)                // 2,359,296 halves

__device__ __forceinline__ int padidx(int p) { return p + 2 * (p / FMPX) + PW + 1; }

// async global->LDS, 16 B per lane
typedef __attribute__((address_space(1))) const void* gas_t;
typedef __attribute__((address_space(3))) void*       las_t;
__device__ __forceinline__ void gl2lds16(const void* g, void* l) {
    __builtin_amdgcn_global_load_lds((gas_t)g, (las_t)l, 16, 0, 0);
}
// raw LDS byte address of a generic pointer into __shared__
__device__ __forceinline__ unsigned lds_addr(void* p) {
    return (unsigned)(uintptr_t)(las_t)p;
}
// inline-asm ds_read_b128: invisible to SIInsertWaitcnts' LDS-DMA alias
// tracking, so no spurious vmcnt drains between in-flight global_load_lds
// (future buffers) and reads of the current buffer.
__device__ __forceinline__ v8h lds_b128(unsigned a) {
    v8h r;
    asm volatile("ds_read_b128 %0, %1" : "=v"(r) : "v"(a));
    return r;
}

// ---------------------------------------------------------------------------
// Zero the padded borders of all 8 feature planes (ws re-poisoned each call).
// ---------------------------------------------------------------------------
__global__ __launch_bounds__(256)
void border_zero(uint4* __restrict__ ws) {
    int idx = blockIdx.x * 256 + threadIdx.x;
    int u    = idx & 63;
    int cell = (idx >> 6) % 164;
    int b    = (idx / (64 * 164)) & 7;
    int pl   = idx / (64 * 164 * 8);          // 0..7
    int pi;
    if (cell < 42)      pi = cell;
    else if (cell < 84) pi = 41 * PW + (cell - 42);
    else { int r = cell - 84; pi = (1 + (r >> 1)) * PW + ((r & 1) ? 41 : 0); }
    size_t hoff = (size_t)pl * FPLANE + (size_t)b * (PADN * CH) + (size_t)pi * CH;
    ws[(hoff >> 3) + u] = make_uint4(0u, 0u, 0u, 0u);
}

// ---------------------------------------------------------------------------
// x [b][512][1600] fp32 -> padded pos-major fp16 hi/lo planes [b][1764][512].
// ---------------------------------------------------------------------------
__global__ __launch_bounds__(256)
void xprep_kernel(const float* __restrict__ x, _Float16* __restrict__ Xh,
                  _Float16* __restrict__ Xl) {
    __shared__ float T[64][65];
    const int t = threadIdx.x;
    const int p0  = blockIdx.x * 64;   // 25
    const int ci0 = blockIdx.y * 64;   // 8
    const int b   = blockIdx.z;        // 8
#pragma unroll
    for (int it = 0; it < 16; ++it) {
        int row = (t >> 6) + 4 * it;
        int col = t & 63;
        T[col][row] = x[((size_t)b * CH + ci0 + row) * NP + p0 + col];
    }
    __syncthreads();
#pragma unroll
    for (int it = 0; it < 16; ++it) {
        int posl = (t >> 6) + 4 * it;
        int ci   = t & 63;
        float v = T[posl][ci];
        _Float16 h = (_Float16)v;
        _Float16 l = (_Float16)((v - (float)h) * 2048.0f);
        size_t o = (size_t)b * (PADN * CH) + (size_t)padidx(p0 + posl) * CH + ci0 + ci;
        Xh[o] = h; Xl[o] = l;
    }
}

// ---------------------------------------------------------------------------
// w [co][ci][3][3] fp32 -> Wh/Wl [tap][co][ci] fp16.
// ---------------------------------------------------------------------------
__global__ __launch_bounds__(256)
void wtrans_kernel(const float* __restrict__ w, _Float16* __restrict__ Wh,
                   _Float16* __restrict__ Wl) {
    __shared__ float tile[32][289];
    const int t = threadIdx.x;
    const int co0 = blockIdx.x * 32;   // 16
    const int ci0 = blockIdx.y * 32;   // 16
#pragma unroll
    for (int g = 0; g < 36; ++g) {     // 32*288 = 9216
        int l = t + 256 * g;
        int co = l / 288, j = l - co * 288;
        tile[co][j] = w[(size_t)(co0 + co) * 4608 + ci0 * 9 + j];
    }
    __syncthreads();
#pragma unroll
    for (int tap = 0; tap < 9; ++tap) {
#pragma unroll
        for (int cg = 0; cg < 4; ++cg) {
            int co = cg * 8 + (t >> 5);
            int ci = t & 31;
            float v = tile[co][ci * 9 + tap];
            _Float16 h = (_Float16)(16.0f * v);
            _Float16 l = (_Float16)((v - (float)h * 0.0625f) * 32768.0f);
            size_t o = ((size_t)tap * CH + co0 + co) * CH + ci0 + ci;
            Wh[o] = h; Wl[o] = l;
        }
    }
}

// ---------------------------------------------------------------------------
// Dual 3x3 conv via MFMA, split-fp16.  r2 skeleton (proven best, 482 us):
//   block = 512 thr / 8 waves, tile 128pos x 256co, wave tile 64pos x 64co,
//   BK=32 chunk = 48 KB, THREE LDS buffers (144 KB), stage split 3+3
//   mid-chunk, COUNTED vmcnt(6) at the barrier (never 0 in main loop).
// ROUND-8: fine counted-lgkm LADDER (T3/T4 proper).  r2's single lgkm(4)
// forced 12/16 reads before the first MFMA -> ~1900-cyc block-wide LDS-port
// stall, then MFMA with idle port (alternation = the 4017-cyc chunk).  Now
// reads issue in consumption order and each MFMA group waits only for its
// own operands; the port streams the rest UNDER the MFMA groups:
//   issue ah01,bh01 | ah23,bh23 | bl0-3 | stage3a
//   lgkm(8) -> G0: acc1[i01][j01]          (4 MFMA)   | issue al0-3
//   lgkm(8) -> G1: acc1 remaining          (12 MFMA)  | stage3b
//   lgkm(4) -> G2: acc2 += ah*bl           (16 MFMA)
//   lgkm(0) -> G3: acc2 += al*bh           (16 MFMA)
//   vmcnt(6) + barrier
// lgkm FIFO max outstanding 12 (<15).  Per-accumulator MFMA order identical
// to r2 (acc1 one product; acc2 ah*bl before al*bh) -> bit-identical output.
// Block decode (1D grid, nconv*208 blocks):
//   b = bid & 7 (XCD swizzle); q = bid >> 3; cid = q/26; r = q%26;
//   cos = r & 1; pt = r >> 1 (0..12); 13th pos tile ragged (guarded store)
// Per-buffer halves: Ah[0,4096) Al[4096,8192) Bh[8192,16384) Bl[16384,24576)
// ---------------------------------------------------------------------------
__global__ __launch_bounds__(512, 2)
void conv_dual(const _Float16* __restrict__ I0h, const _Float16* __restrict__ I0l,
               const _Float16* __restrict__ W0h, const _Float16* __restrict__ W0l,
               const float* __restrict__ bias0,
               _Float16* __restrict__ O0h, _Float16* __restrict__ O0l,
               const _Float16* __restrict__ I1h, const _Float16* __restrict__ I1l,
               const _Float16* __restrict__ W1h, const _Float16* __restrict__ W1l,
               const float* __restrict__ bias1,
               _Float16* __restrict__ O1h, _Float16* __restrict__ O1l) {
    __shared__ _Float16 sm[73728];   // 3 x 24576 halves = 144 KB
    const int t = threadIdx.x;
    const int w = t >> 6, l = t & 63;
    const int quad = l >> 4, col = l & 15;
    const int ph = w >> 2, cq = w & 3;          // wave's pos-half / co-quad

    const int bid = blockIdx.x;
    const int b   = bid & 7;
    const int q   = bid >> 3;
    const int cid = q / 26;
    const int r   = q - 26 * cid;
    const int co0 = (r & 1) * 256;
    const int p0  = (r >> 1) * 128;

    const _Float16* Ih = cid ? I1h : I0h;
    const _Float16* Il = cid ? I1l : I0l;
    const _Float16* Wh = cid ? W1h : W0h;
    const _Float16* Wl = cid ? W1l : W0l;
    const float*  bias = cid ? bias1 : bias0;
    _Float16* Oh = cid ? O1h : O0h;
    _Float16* Ol = cid ? O1l : O0l;

    const size_t boff = (size_t)b * (PADN * CH);

    // staging source bases (halves)
    const size_t sA  = boff + (size_t)padidx(p0 + 16 * w + col) * CH + quad * 8;
    const size_t sB0 = (size_t)(co0 + 32 * w + col) * CH + quad * 8;
    // staging dests within a buffer (halves)
    const int dA = w * 512 + l * 8;                    // A-hi; A-lo at +4096
    const int dB = 8192 + (2 * w) * 512 + l * 8;       // B-hi; B-lo at +8192

    // fragment read byte-addresses (buffer 0); + bufB selects buffer
    const unsigned smB = lds_addr(sm);
    unsigned aRh[4], aRl[4], bRh[4], bRl[4];
#pragma unroll
    for (int i = 0; i < 4; ++i) {
        aRh[i] = smB + (ph * 4 + i) * 1024 + l * 16;
        aRl[i] = aRh[i] + 8192;
    }
#pragma unroll
    for (int j = 0; j < 4; ++j) {
        bRh[j] = smB + 16384 + (cq * 4 + j) * 1024 + l * 16;
        bRl[j] = bRh[j] + 16384;
    }

    // staging pointer state (points at chunk to be staged next)
    const _Float16 *pAh, *pAl, *pWh, *pWl;
    auto set_stage = [&](int ms) {
        const int tap = ms >> 4, cc = (ms & 15) << 5;
        const int ty  = tap / 3;
        const int tsh = ((ty - 1) * PW + (tap - ty * 3 - 1)) * CH + cc;
        const size_t wo = (size_t)tap * (CH * CH) + cc;
        pAh = Ih + sA + tsh;  pAl = Il + sA + tsh;
        pWh = Wh + wo + sB0;  pWl = Wl + wo + sB0;
    };
    auto stage3a = [&](unsigned nH) {
        _Float16* dst = sm + nH;
        gl2lds16(pAh,           dst + dA);
        gl2lds16(pAl,           dst + 4096 + dA);
        gl2lds16(pWh,           dst + dB);
    };
    auto stage3b = [&](unsigned nH) {
        _Float16* dst = sm + nH;
        gl2lds16(pWh + 16 * CH, dst + dB + 512);
        gl2lds16(pWl,           dst + 8192 + dB);
        gl2lds16(pWl + 16 * CH, dst + 8192 + dB + 512);
    };

    v4f acc1[4][4], acc2[4][4];
#pragma unroll
    for (int i = 0; i < 4; ++i)
#pragma unroll
        for (int j = 0; j < 4; ++j) {
            acc1[i][j] = (v4f){0.f, 0.f, 0.f, 0.f};
            acc2[i][j] = (v4f){0.f, 0.f, 0.f, 0.f};
        }

    // prologue: stage chunks 0 and 1; wait only for chunk 0 (vmcnt(6))
    set_stage(0); stage3a(0);     stage3b(0);
    set_stage(1); stage3a(24576); stage3b(24576);
    set_stage(2);
    asm volatile("s_waitcnt vmcnt(6)" ::: "memory");
    __builtin_amdgcn_s_barrier();

    unsigned c0H = 0, c1H = 24576, c2H = 49152;   // read / next / stage target

#pragma unroll 1
    for (int m = 0; m < 144; ++m) {               // 9 taps x 16 k-chunks
        const unsigned bufB = c0H * 2;            // read buffer, bytes

        v8h ah[4], al[4], bh[4], bl[4];
        // reads in consumption order: ah01,bh01 | ah23,bh23 | bl0-3
        ah[0] = lds_b128(aRh[0] + bufB);
        ah[1] = lds_b128(aRh[1] + bufB);
        bh[0] = lds_b128(bRh[0] + bufB);
        bh[1] = lds_b128(bRh[1] + bufB);
        ah[2] = lds_b128(aRh[2] + bufB);
        ah[3] = lds_b128(aRh[3] + bufB);
        bh[2] = lds_b128(bRh[2] + bufB);
        bh[3] = lds_b128(bRh[3] + bufB);
        bl[0] = lds_b128(bRl[0] + bufB);
        bl[1] = lds_b128(bRl[1] + bufB);
        bl[2] = lds_b128(bRl[2] + bufB);
        bl[3] = lds_b128(bRl[3] + bufB);

        // stage first half of chunk m+2 (3 vm ops)
        if (m < 142) stage3a(c2H);

        // G0: needs ah01,bh01 only (forces 4 oldest; 8 stay in flight)
        asm volatile("s_waitcnt lgkmcnt(8)" ::: "memory");
        __builtin_amdgcn_sched_barrier(0);   // rule #18
        __builtin_amdgcn_s_setprio(1);
        acc1[0][0] = __builtin_amdgcn_mfma_f32_16x16x32_f16(ah[0], bh[0], acc1[0][0], 0, 0, 0);
        acc1[1][0] = __builtin_amdgcn_mfma_f32_16x16x32_f16(ah[1], bh[0], acc1[1][0], 0, 0, 0);
        acc1[0][1] = __builtin_amdgcn_mfma_f32_16x16x32_f16(ah[0], bh[1], acc1[0][1], 0, 0, 0);
        acc1[1][1] = __builtin_amdgcn_mfma_f32_16x16x32_f16(ah[1], bh[1], acc1[1][1], 0, 0, 0);
        __builtin_amdgcn_s_setprio(0);

        // issue al0-3 (outstanding: ah23,bh23 + bl0-3 + al0-3 <= 12)
        al[0] = lds_b128(aRl[0] + bufB);
        al[1] = lds_b128(aRl[1] + bufB);
        al[2] = lds_b128(aRl[2] + bufB);
        al[3] = lds_b128(aRl[3] + bufB);

        // G1: needs ah23,bh23 (forces them; bl+al stay in flight)
        asm volatile("s_waitcnt lgkmcnt(8)" ::: "memory");
        __builtin_amdgcn_sched_barrier(0);
        __builtin_amdgcn_s_setprio(1);
        acc1[2][0] = __builtin_amdgcn_mfma_f32_16x16x32_f16(ah[2], bh[0], acc1[2][0], 0, 0, 0);
        acc1[3][0] = __builtin_amdgcn_mfma_f32_16x16x32_f16(ah[3], bh[0], acc1[3][0], 0, 0, 0);
        acc1[2][1] = __builtin_amdgcn_mfma_f32_16x16x32_f16(ah[2], bh[1], acc1[2][1], 0, 0, 0);
        acc1[3][1] = __builtin_amdgcn_mfma_f32_16x16x32_f16(ah[3], bh[1], acc1[3][1], 0, 0, 0);
#pragma unroll
        for (int i = 0; i < 4; ++i)
            acc1[i][2] = __builtin_amdgcn_mfma_f32_16x16x32_f16(ah[i], bh[2], acc1[i][2], 0, 0, 0);
#pragma unroll
        for (int i = 0; i < 4; ++i)
            acc1[i][3] = __builtin_amdgcn_mfma_f32_16x16x32_f16(ah[i], bh[3], acc1[i][3], 0, 0, 0);
        __builtin_amdgcn_s_setprio(0);

        // stage second half of chunk m+2; advance staging pointers
        if (m < 142) {
            stage3b(c2H);
            const int nxt = m + 3;
            if (nxt < 144) {
                if ((nxt & 15) == 0) set_stage(nxt);
                else { pAh += 32; pAl += 32; pWh += 32; pWl += 32; }
            }
        }

        // G2: needs bl0-3 (forces them; al stays in flight)
        asm volatile("s_waitcnt lgkmcnt(4)" ::: "memory");
        __builtin_amdgcn_sched_barrier(0);
        __builtin_amdgcn_s_setprio(1);
#pragma unroll
        for (int j = 0; j < 4; ++j)
#pragma unroll
            for (int i = 0; i < 4; ++i)
                acc2[i][j] = __builtin_amdgcn_mfma_f32_16x16x32_f16(ah[i], bl[j], acc2[i][j], 0, 0, 0);
        __builtin_amdgcn_s_setprio(0);

        // G3: needs al0-3
        asm volatile("s_waitcnt lgkmcnt(0)" ::: "memory");
        __builtin_amdgcn_sched_barrier(0);
        __builtin_amdgcn_s_setprio(1);
#pragma unroll
        for (int j = 0; j < 4; ++j)
#pragma unroll
            for (int i = 0; i < 4; ++i)
                acc2[i][j] = __builtin_amdgcn_mfma_f32_16x16x32_f16(al[i], bh[j], acc2[i][j], 0, 0, 0);
        __builtin_amdgcn_s_setprio(0);

        // barrier with COUNTED vmcnt: chunk m+1 staged (its 6 loads retired),
        // chunk m+2's 6 loads may stay in flight. lgkm already drained.
        if (m < 142) {
            asm volatile("s_waitcnt vmcnt(6)" ::: "memory");
            __builtin_amdgcn_s_barrier();
        } else if (m == 142) {
            asm volatile("s_waitcnt vmcnt(0)" ::: "memory");
            __builtin_amdgcn_s_barrier();
        }
        unsigned tmp = c0H; c0H = c1H; c1H = c2H; c2H = tmp;
    }

    // epilogue: combine, bias, leaky, split-store. guard ragged pos tile.
#pragma unroll
    for (int i = 0; i < 4; ++i) {
#pragma unroll
        for (int j = 0; j < 4; ++j) {
            int n = co0 + cq * 64 + j * 16 + col;
            float bv = bias[n];
#pragma unroll
            for (int rr = 0; rr < 4; ++rr) {
                int p = p0 + ph * 64 + i * 16 + quad * 4 + rr;
                if (p < NP) {
                    float v = acc1[i][j][rr] * 0.0625f + acc2[i][j][rr] * (1.0f / 32768.0f) + bv;
                    v = v > 0.f ? v : 0.1f * v;
                    _Float16 h = (_Float16)v;
                    _Float16 lo = (_Float16)((v - (float)h) * 2048.0f);
                    size_t o = boff + (size_t)padidx(p) * CH + n;
                    Oh[o] = h; Ol[o] = lo;
                }
            }
        }
    }
}

// ---------------------------------------------------------------------------
// Head: 1x1 convs + decode. One wave per (b,pos); lanes split ci (64x8=512).
// ---------------------------------------------------------------------------
__global__ __launch_bounds__(256)
void head_kernel(const _Float16* __restrict__ Rh, const _Float16* __restrict__ Rl,
                 const _Float16* __restrict__ Ch, const _Float16* __restrict__ Cl,
                 const float* __restrict__ objw, const float* __restrict__ objb,
                 const float* __restrict__ clsw, const float* __restrict__ clsb,
                 const float* __restrict__ regw, const float* __restrict__ regb,
                 float* __restrict__ out) {
    const int wid = (blockIdx.x * 256 + threadIdx.x) >> 6;  // 0..12799
    const int l = threadIdx.x & 63;
    const int b = wid / NP, p = wid - b * NP;
    const size_t base = (size_t)b * (PADN * CH) + (size_t)padidx(p) * CH + l * 8;

    v8h rh = *(const v8h*)(Rh + base), rl = *(const v8h*)(Rl + base);
    v8h ch = *(const v8h*)(Ch + base), cl = *(const v8h*)(Cl + base);
    float rv[8], cv[8];
#pragma unroll
    for (int k = 0; k < 8; ++k) {
        rv[k] = (float)rh[k] + (float)rl[k] * (1.0f / 2048.0f);
        cv[k] = (float)ch[k] + (float)cl[k] * (1.0f / 2048.0f);
    }
    float s[25];
#pragma unroll
    for (int o = 0; o < 25; ++o) s[o] = 0.f;
#pragma unroll
    for (int k = 0; k < 8; ++k) s[0] = fmaf(objw[l * 8 + k], rv[k], s[0]);
#pragma unroll
    for (int c = 0; c < NCLS; ++c)
#pragma unroll
        for (int k = 0; k < 8; ++k) s[1 + c] = fmaf(clsw[c * CH + l * 8 + k], cv[k], s[1 + c]);
#pragma unroll
    for (int q = 0; q < 4; ++q)
#pragma unroll
        for (int k = 0; k < 8; ++k) s[21 + q] = fmaf(regw[q * CH + l * 8 + k], rv[k], s[21 + q]);
#pragma unroll
    for (int o = 0; o < 25; ++o) {
#pragma unroll
        for (int off = 32; off > 0; off >>= 1) s[o] += __shfl_xor(s[o], off);
    }
    if (l == 0) {
        int gp = b * NP + p;
        float obj  = s[0] + objb[0];
        float sobj = 1.f / (1.f + expf(-obj));
        float lg[NCLS];
        float m = -1e30f; int am = 0;
#pragma unroll
        for (int c = 0; c < NCLS; ++c) {
            lg[c] = s[1 + c] + clsb[c];
            if (lg[c] > m) { m = lg[c]; am = c; }
        }
        float se = 0.f;
#pragma unroll
        for (int c = 0; c < NCLS; ++c) se += expf(lg[c] - m);
        float best = sobj / se;

        float r0 = s[21] + regb[0], r1 = s[22] + regb[1];
        float r2 = s[23] + regb[2], r3 = s[24] + regb[3];
        int gy = p / FMPX, gx = p - gy * FMPX;
        float cx = 1.f / (1.f + expf(-r0)) + (float)gx;
        float cy = 1.f / (1.f + expf(-r1)) + (float)gy;
        float hw = 0.5f * expf(r2);
        float hh = 0.5f * expf(r3);
        const float sc = 32.f / 1280.f;
        float x1 = fminf(fmaxf((cx - hw) * sc, 0.f), 1.f);
        float y1 = fminf(fmaxf((cy - hh) * sc, 0.f), 1.f);
        float x2 = fminf(fmaxf((cx + hw) * sc, 0.f), 1.f);
        float y2 = fminf(fmaxf((cy + hh) * sc, 0.f), 1.f);

        ((float4*)out)[gp] = make_float4(x1, y1, x2, y2);
        out[4 * BATCH * NP + gp] = best;
        out[5 * BATCH * NP + gp] = (float)am;
        out[6 * BATCH * NP + gp] = 0.f;
    }
}

// ---------------------------------------------------------------------------
// Sort-based greedy NMS: 1024 thr, MLP kept-scan, shfl resolve. (unchanged)
// ---------------------------------------------------------------------------
__global__ __launch_bounds__(1024)
void nms_kernel(float* __restrict__ out) {
    const int c = blockIdx.x, b = blockIdx.y;
    const int t = threadIdx.x;
    const int w = t >> 6, l = t & 63;

    __shared__ unsigned long long skey[2048];
    __shared__ float4 CBox[NP];
    __shared__ float4 KBox[1664];
    __shared__ unsigned long long wmask[16];
    __shared__ int Kcnt;

    for (int j = t; j < NP; j += 1024) {
        int gp = b * NP + j;
        float4 bx = ((const float4*)out)[gp];
        float best = out[4 * BATCH * NP + gp];
        int   ci   = (int)out[5 * BATCH * NP + gp];
        CBox[j] = bx;
        bool alive = (ci == c) && (best >= CONF_THR);
        unsigned long long key = alive
            ? ~(((unsigned long long)__float_as_uint(best) << 32)
                | (unsigned long long)(0xFFFFFFFFu - (unsigned)j))
            : ~0ull;
        skey[j] = key;
    }
    for (int j = NP + t; j < 2048; j += 1024) skey[j] = ~0ull;
    for (int j = t; j < 1664; j += 1024) KBox[j] = make_float4(0.f, 0.f, 0.f, 0.f);
    if (t == 0) Kcnt = 0;

    for (unsigned k = 2; k <= 2048; k <<= 1) {
        for (unsigned j = k >> 1; j > 0; j >>= 1) {
            __syncthreads();
            for (unsigned i = t; i < 2048; i += 1024) {
                unsigned p = i ^ j;
                if (p > i) {
                    bool up = ((i & k) == 0);
                    unsigned long long a = skey[i], bq = skey[p];
                    if ((a > bq) == up) { skey[i] = bq; skey[p] = a; }
                }
            }
        }
    }
    __syncthreads();

    float* keepout = out + 6 * BATCH * NP + b * NP;
    for (int base = 0; base < NP; base += 64) {
        unsigned long long ik = skey[base + l];
        bool valid = (ik != ~0ull);
        unsigned long long vm = __ballot(valid);
        if (vm == 0) break;

        unsigned idx = 0;
        float4 bx = make_float4(0.f, 0.f, 0.f, 0.f);
        float ar = 0.f;
        if (valid) {
            unsigned long long K = ~ik;
            idx = 0xFFFFFFFFu - (unsigned)(K & 0xFFFFFFFFull);
            bx  = CBox[idx];
            ar  = (bx.z - bx.x) * (bx.w - bx.y);
        }
        int prevK = Kcnt;
        int prevKpad = (prevK + 63) & ~63;

        bool sup = false;
        for (int kk = w * 4; kk < prevKpad; kk += 64) {
            float4 kb0 = KBox[kk],     kb1 = KBox[kk + 1];
            float4 kb2 = KBox[kk + 2], kb3 = KBox[kk + 3];
#pragma unroll
            for (int q = 0; q < 4; ++q) {
                float4 kb = q == 0 ? kb0 : q == 1 ? kb1 : q == 2 ? kb2 : kb3;
                float kar = (kb.z - kb.x) * (kb.w - kb.y);
                float xx1 = fmaxf(kb.x, bx.x);
                float yy1 = fmaxf(kb.y, bx.y);
                float xx2 = fminf(kb.z, bx.z);
                float yy2 = fminf(kb.w, bx.w);
                float ww = fmaxf(1e-28f, xx2 - xx1);
                float hh = fmaxf(1e-28f, yy2 - yy1);
                float inter = ww * hh;
                float iou = inter / (kar + ar - inter + 1e-14f);
                sup |= (iou > NMS_THR);
            }
        }
        wmask[w] = __ballot(valid && !sup);
        __syncthreads();

        if (w == 0) {
            unsigned long long alive = wmask[0];
#pragma unroll
            for (int q = 1; q < 16; ++q) alive &= wmask[q];
            unsigned long long smask = 0;
            for (int s = 0; s < 63; ++s) {
                float ox1 = __shfl(bx.x, s), oy1 = __shfl(bx.y, s);
                float ox2 = __shfl(bx.z, s), oy2 = __shfl(bx.w, s);
                float oar = (ox2 - ox1) * (oy2 - oy1);
                float xx1 = fmaxf(ox1, bx.x);
                float yy1 = fmaxf(oy1, bx.y);
                float xx2 = fminf(ox2, bx.z);
                float yy2 = fminf(oy2, bx.w);
                float ww = fmaxf(1e-28f, xx2 - xx1);
                float hh = fmaxf(1e-28f, yy2 - yy1);
                float inter = ww * hh;
                float iou = inter / (oar + ar - inter + 1e-14f);
                if (s < l && iou > NMS_THR) smask |= (1ull << s);
            }
            unsigned long long kept = 0;
            while (alive) {
                int s = __builtin_ctzll(alive);
                kept |= (1ull << s);
                alive &= ~(1ull << s);
                unsigned long long dead = __ballot((smask >> s) & 1ull);
                alive &= ~dead;
            }
            if ((kept >> l) & 1ull) {
                int pos = prevK + __builtin_popcountll(kept & ((1ull << l) - 1ull));
                KBox[pos] = bx;
                keepout[idx] = 1.0f;
            }
            if (l == 0) Kcnt = prevK + __builtin_popcountll(kept);
        }
        __syncthreads();
    }
}

// ---------------------------------------------------------------------------
extern "C" void kernel_launch(void* const* d_in, const int* in_sizes, int n_in,
                              void* d_out, int out_size, void* d_ws, size_t ws_size,
                              hipStream_t stream) {
    const float* x      = (const float*)d_in[0];
    const float* cls_w  = (const float*)d_in[1];
    const float* cls_b  = (const float*)d_in[2];
    const float* reg_w  = (const float*)d_in[3];
    const float* reg_b  = (const float*)d_in[4];
    const float* obj_w  = (const float*)d_in[5];
    const float* obj_b  = (const float*)d_in[6];
    const float* clsp_w = (const float*)d_in[7];
    const float* clsp_b = (const float*)d_in[8];
    const float* regp_w = (const float*)d_in[9];
    const float* regp_b = (const float*)d_in[10];
    float* out = (float*)d_out;

    _Float16* ws = (_Float16*)d_ws;
    _Float16* Xh = ws;                     // pair 0
    _Float16* Xl = ws + FPLANE;
    _Float16* Ah = ws + 2 * FPLANE;        // pair 1
    _Float16* Al = ws + 3 * FPLANE;
    _Float16* Bh = ws + 4 * FPLANE;        // pair 2
    _Float16* Bl = ws + 5 * FPLANE;
    _Float16* Ch = ws + 6 * FPLANE;        // pair 3
    _Float16* Cl = ws + 7 * FPLANE;
    _Float16* W0h = ws + 8 * FPLANE;       // weight set 0
    _Float16* W0l = W0h + WSZ;
    _Float16* W1h = W0l + WSZ;             // weight set 1
    _Float16* W1l = W1h + WSZ;
    const size_t LW = (size_t)CH * CH * 9;

    border_zero<<<dim3(2624), 256, 0, stream>>>((uint4*)d_ws);
    xprep_kernel<<<dim3(25, 8, 8), 256, 0, stream>>>(x, Xh, Xl);

    dim3 wgrid(16, 16), blk(256);

    // D1: cls1 (X->A) || reg1 (X->C)
    wtrans_kernel<<<wgrid, blk, 0, stream>>>(cls_w, W0h, W0l);
    wtrans_kernel<<<wgrid, blk, 0, stream>>>(reg_w, W1h, W1l);
    conv_dual<<<dim3(416), 512, 0, stream>>>(Xh, Xl, W0h, W0l, cls_b,      Ah, Al,
                                             Xh, Xl, W1h, W1l, reg_b,      Ch, Cl);
    // D2: cls2 (A->B) || reg2 (C->X)
    wtrans_kernel<<<wgrid, blk, 0, stream>>>(cls_w + LW, W0h, W0l);
    wtrans_kernel<<<wgrid, blk, 0, stream>>>(reg_w + LW, W1h, W1l);
    conv_dual<<<dim3(416), 512, 0, stream>>>(Ah, Al, W0h, W0l, cls_b + CH, Bh, Bl,
                                             Ch, Cl, W1h, W1l, reg_b + CH, Xh, Xl);
    // D3: reg3 (X->C)
    wtrans_kernel<<<wgrid, blk, 0, stream>>>(reg_w + 2 * LW, W0h, W0l);
    conv_dual<<<dim3(208), 512, 0, stream>>>(Xh, Xl, W0h, W0l, reg_b + 2 * CH, Ch, Cl,
                                             Xh, Xl, W0h, W0l, reg_b + 2 * CH, Ch, Cl);
    // D4: reg4 (C->X)
    wtrans_kernel<<<wgrid, blk, 0, stream>>>(reg_w + 3 * LW, W0h, W0l);
    conv_dual<<<dim3(208), 512, 0, stream>>>(Ch, Cl, W0h, W0l, reg_b + 3 * CH, Xh, Xl,
                                             Ch, Cl, W0h, W0l, reg_b + 3 * CH, Xh, Xl);

    head_kernel<<<dim3(3200), 256, 0, stream>>>(Xh, Xl, Bh, Bl, obj_w, obj_b,
                                                clsp_w, clsp_b, regp_w, regp_b, out);
    nms_kernel<<<dim3(NCLS, BATCH), 1024, 0, stream>>>(out);
}